// Round 10
// baseline (693.743 us; speedup 1.0000x reference)
//
#include <hip/hip_runtime.h>
#include <hip/hip_bf16.h>
#include <math.h>

#define N_NODES 10000
#define N_EDGES 320000
#define CH 64
#define MIXW 192        // N_L * CH
#define AGG_STRIDE 576  // agg[node][m*64 + ch], m = 0..8
#define SH_STRIDE 9     // LDS sh row stride (9 coprime 32 -> conflict-free writes)

// weight-image layout (shorts), stride-72 rows (16B-aligned row starts)
#define W1_OFF 0        // [64][8]
#define W2_OFF 512      // [64][72]
#define W3_OFF 5120     // [64][72]
#define W4_OFF 9728     // [192][72]
#define W_TOT 23552     // shorts
#define ACT_STRIDE 72

#define EPB 128         // edges per k_mlp block (256 thr = 4 waves, 32 edges/wave)

// fused k_pre block ranges (histogram removed -- no CSR anymore)
#define PREP_BLKS 92            // 23552/256
#define H_BLKS 625              // 10000 nodes / (4 waves * 4 nodes-per-wave)

typedef __attribute__((ext_vector_type(8))) short bf16x8;
typedef __attribute__((ext_vector_type(4))) float f32x4;
#define MFMA16(a, b, c) __builtin_amdgcn_mfma_f32_16x16x32_bf16(a, b, c, 0, 0, 0)

// ---------- small helpers ----------
__device__ __forceinline__ float bf2f(unsigned short u) {
    union { unsigned int i; float f; } v; v.i = ((unsigned int)u) << 16; return v.f;
}
__device__ __forceinline__ unsigned short f2bf(float f) {
    __hip_bfloat16 b = __float2bfloat16(f);
    return *reinterpret_cast<unsigned short*>(&b);
}
__device__ __forceinline__ float silu(float t) {
    return t * __builtin_amdgcn_rcpf(1.0f + __expf(-t));
}

// load a [64]->[64] layer's B-fragments (8 x b128 from L2-resident wimg)
__device__ __forceinline__ void load_bfrag(bf16x8 (&b)[4][2],
                                           const unsigned short* __restrict__ wbase,
                                           int lrow, int quad) {
#pragma unroll
    for (int nt = 0; nt < 4; ++nt)
#pragma unroll
        for (int kh = 0; kh < 2; ++kh)
            b[nt][kh] = *(const bf16x8*)(wbase + (nt * 16 + lrow) * 72 + kh * 32 + quad * 8);
}

// one in-place [64]->[64] MFMA layer with silu (scales pre-folded into weights)
__device__ __forceinline__ void layer64(unsigned short* act, const bf16x8 (&b)[4][2],
                                        int em0, int em1, int cr0, int cr1,
                                        int lrow, int quad) {
    bf16x8 a00 = *(const bf16x8*)(act + em0 * ACT_STRIDE + quad * 8);
    bf16x8 a01 = *(const bf16x8*)(act + em0 * ACT_STRIDE + 32 + quad * 8);
    bf16x8 a10 = *(const bf16x8*)(act + em1 * ACT_STRIDE + quad * 8);
    bf16x8 a11 = *(const bf16x8*)(act + em1 * ACT_STRIDE + 32 + quad * 8);
#pragma unroll
    for (int nt = 0; nt < 4; ++nt) {
        f32x4 c0 = {0.f, 0.f, 0.f, 0.f};
        f32x4 c1 = {0.f, 0.f, 0.f, 0.f};
        c0 = MFMA16(a00, b[nt][0], c0);
        c0 = MFMA16(a01, b[nt][1], c0);
        c1 = MFMA16(a10, b[nt][0], c1);
        c1 = MFMA16(a11, b[nt][1], c1);
#pragma unroll
        for (int r = 0; r < 4; ++r) {
            act[(cr0 + r) * ACT_STRIDE + nt * 16 + lrow] = f2bf(silu(c0[r]));
            act[(cr1 + r) * ACT_STRIDE + nt * 16 + lrow] = f2bf(silu(c1[r]));
        }
    }
}

// one third (64 cols = one l) of layer 4: MFMA + h-premult (single rounding
// f2bf(c*h), R9 numerics) -> LDS stage -> FUSED scatter: fire-and-forget
// f32 atomicAdd of w*sh[m] into agg[node][m*64+ch]. No hw intermediate.
__device__ __forceinline__ void l4_third_agg(unsigned short* act,
                                             const int* s_rcv,
                                             const float* s_sh,
                                             float* __restrict__ agg,
                                             const bf16x8 (&b)[4][2],
                                             const bf16x8& a00, const bf16x8& a01,
                                             const bf16x8& a10, const bf16x8& a11,
                                             const float (&hreg0)[4][4],
                                             const float (&hreg1)[4][4],
                                             int T, int cr0, int cr1, int wr0,
                                             int lane, int lrow, int quad) {
#pragma unroll
    for (int ntl = 0; ntl < 4; ++ntl) {
        f32x4 c0 = {0.f, 0.f, 0.f, 0.f};
        f32x4 c1 = {0.f, 0.f, 0.f, 0.f};
        c0 = MFMA16(a00, b[ntl][0], c0);
        c0 = MFMA16(a01, b[ntl][1], c0);
        c1 = MFMA16(a10, b[ntl][0], c1);
        c1 = MFMA16(a11, b[ntl][1], c1);
#pragma unroll
        for (int r = 0; r < 4; ++r) {
            act[(cr0 + r) * ACT_STRIDE + ntl * 16 + lrow] = f2bf(c0[r] * hreg0[r][ntl]);
            act[(cr1 + r) * ACT_STRIDE + ntl * 16 + lrow] = f2bf(c1[r] * hreg1[r][ntl]);
        }
    }
    // scatter wave's 32 rows: per row, lane=ch reads staged w (128B LDS line),
    // atomicAdd into node accumulator (64-lane contiguous 256B per m).
    // Atomics return nothing -> no vmcnt wait; they drain at kernel end.
#pragma unroll 8
    for (int r = 0; r < 32; ++r) {
        int row = wr0 + r;
        int node = __builtin_amdgcn_readfirstlane(s_rcv[row]);
        float w = bf2f(act[row * ACT_STRIDE + lane]);
        float* ab = agg + (size_t)node * AGG_STRIDE + lane;
        const float* shr = s_sh + row * SH_STRIDE;
        if (T == 0) {
            atomicAdd(ab, w);                          // sh[0] == 1.0
        } else if (T == 1) {
            atomicAdd(ab + 64, w * shr[1]);
            atomicAdd(ab + 128, w * shr[2]);
            atomicAdd(ab + 192, w * shr[3]);
        } else {
            atomicAdd(ab + 256, w * shr[4]);
            atomicAdd(ab + 320, w * shr[5]);
            atomicAdd(ab + 384, w * shr[6]);
            atomicAdd(ab + 448, w * shr[7]);
            atomicAdd(ab + 512, w * shr[8]);
        }
    }
}

// ---------- K_pre: weight-prep + linear_up (histogram/CSR machinery deleted) --
// Scale folding: W1 *= 1/sqrt(8) (f32, then bf16); W2,W3 *= 1/8 (pow2, bit-exact
// in bf16); W4 unscaled; h = (nf@Wup)/64 in f32 (linear_up 1/8 * mlp4 1/8).
__global__ __launch_bounds__(256) void k_pre(const float* __restrict__ W1,
                                             const float* __restrict__ W2,
                                             const float* __restrict__ W3,
                                             const float* __restrict__ W4,
                                             unsigned short* __restrict__ wimg,
                                             const float* __restrict__ nf,
                                             const float* __restrict__ Wup,
                                             float* __restrict__ h) {
    int bid = blockIdx.x;
    int t = threadIdx.x;
    if (bid < PREP_BLKS) {
        int i = bid * 256 + t;
        if (i >= W_TOT) return;
        float v;
        if (i < W2_OFF) {
            int n = i >> 3, k = i & 7;
            v = W1[k * 64 + n] * 0.35355339059327376f;
        } else if (i < W3_OFF) {
            int j = i - W2_OFF; int n = j / 72, k = j % 72;
            v = (k < 64) ? W2[k * 64 + n] * 0.125f : 0.f;
        } else if (i < W4_OFF) {
            int j = i - W3_OFF; int n = j / 72, k = j % 72;
            v = (k < 64) ? W3[k * 64 + n] * 0.125f : 0.f;
        } else {
            int j = i - W4_OFF; int n = j / 72, k = j % 72;
            v = (k < 64) ? W4[k * MIXW + n] : 0.f;
        }
        wimg[i] = f2bf(v);
    } else {
        // linear_up: 4 nodes per wave -- Wup column loaded once, 4 indep chains
        int nb = __builtin_amdgcn_readfirstlane(
            (bid - PREP_BLKS) * 16 + (t >> 6) * 4);
        int lane = t & 63;
        const float* nrow = nf + (size_t)nb * CH;
        float a0 = 0.f, a1 = 0.f, a2 = 0.f, a3 = 0.f;
#pragma unroll
        for (int k = 0; k < CH; ++k) {
            float w = Wup[k * CH + lane];
            a0 = fmaf(nrow[k], w, a0);
            a1 = fmaf(nrow[CH + k], w, a1);
            a2 = fmaf(nrow[2 * CH + k], w, a2);
            a3 = fmaf(nrow[3 * CH + k], w, a3);
        }
        // 1/8 (linear_up) * 1/8 (mlp4) folded into h
        h[(size_t)nb * CH + lane] = a0 * 0.015625f;
        h[(size_t)(nb + 1) * CH + lane] = a1 * 0.015625f;
        h[(size_t)(nb + 2) * CH + lane] = a2 * 0.015625f;
        h[(size_t)(nb + 3) * CH + lane] = a3 * 0.015625f;
    }
}

// ---------- K_mlp v16: fused MLP + scatter-aggregate (no hw, no erec) -------
// 256 thr = 4 waves; 128 edges/block; 2 A-tiles/wave (the VGPR-safe h config:
// 68 VGPR). Edges in ORIGINAL order (coalesced ev/rad/senders/recv reads; no
// CSR cursor). sh[9] lives in LDS; per third, messages go straight to
// agg[node][m][ch] via fire-and-forget f32 atomics (device scope, L2-resident
// 23MB table). Eliminates the 246MB hw round-trip + 41MB erec.
__global__ __launch_bounds__(256) void k_mlp(const float* __restrict__ ev,
                                             const float* __restrict__ rad,
                                             const unsigned short* __restrict__ wimg,
                                             const int* __restrict__ senders,
                                             const int* __restrict__ recv,
                                             const float* __restrict__ h,
                                             float* __restrict__ agg) {
    __shared__ unsigned short act[EPB * ACT_STRIDE];     // 18432 B
    __shared__ int s_rcv[EPB];                           // 512 B
    __shared__ int s_snd[EPB];                           // 512 B
    __shared__ float s_sh[EPB * SH_STRIDE];              // 4608 B

    const int t = threadIdx.x;
    const int e0 = blockIdx.x * EPB;
    const int wv = t >> 6;
    const int lane = t & 63;
    const int lrow = lane & 15;
    const int quad = lane >> 4;
    const int wr0 = wv * 32;                 // this wave's first act row
    const int em0 = wr0 + lrow;              // A-tile0 row
    const int em1 = em0 + 16;                // A-tile1 row
    const int cr0 = wr0 + quad * 4;          // tile0 C-row base
    const int cr1 = cr0 + 16;                // tile1 C-row base

    // ---- prefetch: radial frags + W1 (quad 0) + W2 (all lanes) ----
    bf16x8 ar0 = {0, 0, 0, 0, 0, 0, 0, 0};
    bf16x8 ar1 = {0, 0, 0, 0, 0, 0, 0, 0};
    bf16x8 bw1[4];
#pragma unroll
    for (int nt = 0; nt < 4; ++nt) bw1[nt] = (bf16x8){0, 0, 0, 0, 0, 0, 0, 0};
    if (quad == 0) {
        const float4* rp0 = (const float4*)(rad + (size_t)(e0 + em0) * 8);
        const float4* rp1 = (const float4*)(rad + (size_t)(e0 + em1) * 8);
        float4 u = rp0[0], v = rp0[1];
        ar0[0] = (short)f2bf(u.x); ar0[1] = (short)f2bf(u.y);
        ar0[2] = (short)f2bf(u.z); ar0[3] = (short)f2bf(u.w);
        ar0[4] = (short)f2bf(v.x); ar0[5] = (short)f2bf(v.y);
        ar0[6] = (short)f2bf(v.z); ar0[7] = (short)f2bf(v.w);
        u = rp1[0]; v = rp1[1];
        ar1[0] = (short)f2bf(u.x); ar1[1] = (short)f2bf(u.y);
        ar1[2] = (short)f2bf(u.z); ar1[3] = (short)f2bf(u.w);
        ar1[4] = (short)f2bf(v.x); ar1[5] = (short)f2bf(v.y);
        ar1[6] = (short)f2bf(v.z); ar1[7] = (short)f2bf(v.w);
#pragma unroll
        for (int nt = 0; nt < 4; ++nt)
            bw1[nt] = *(const bf16x8*)(wimg + W1_OFF + (nt * 16 + lrow) * 8);
    }
    bf16x8 bA[4][2], bB[4][2];
    load_bfrag(bA, wimg + W2_OFF, lrow, quad);           // L2 weights, early

    // ---- phase 0 (lanes 0..31): receiver + sender + SH into LDS ----
    // (same-wave in-order DS: later reads by this wave need no barrier)
    if (lane < 32) {
        int row = wr0 + lane;
        int e = e0 + row;
        s_rcv[row] = recv[e];
        s_snd[row] = senders[e];
        float vx = ev[(size_t)e * 3 + 0], vy = ev[(size_t)e * 3 + 1], vz = ev[(size_t)e * 3 + 2];
        float inv = rsqrtf(vx * vx + vy * vy + vz * vz);
        float x = vx * inv, y = vy * inv, z = vz * inv;
        const float s3 = 1.7320508075688772f;
        const float s15 = 3.872983346207417f;
        const float s5 = 2.2360679774997896f;
        float* shr = s_sh + row * SH_STRIDE;
        shr[0] = 1.0f;
        shr[1] = s3 * x;
        shr[2] = s3 * y;
        shr[3] = s3 * z;
        shr[4] = s15 * x * y;
        shr[5] = s15 * y * z;
        shr[6] = 0.5f * s5 * (3.0f * z * z - 1.0f);
        shr[7] = s15 * x * z;
        shr[8] = 0.5f * s15 * (x * x - y * y);
    }

    // ---- layer 1: [8]->[64] (scale folded into W1), silu ----
#pragma unroll
    for (int nt = 0; nt < 4; ++nt) {
        f32x4 c0 = {0.f, 0.f, 0.f, 0.f};
        f32x4 c1 = {0.f, 0.f, 0.f, 0.f};
        c0 = MFMA16(ar0, bw1[nt], c0);
        c1 = MFMA16(ar1, bw1[nt], c1);
#pragma unroll
        for (int r = 0; r < 4; ++r) {
            act[(cr0 + r) * ACT_STRIDE + nt * 16 + lrow] = f2bf(silu(c0[r]));
            act[(cr1 + r) * ACT_STRIDE + nt * 16 + lrow] = f2bf(silu(c1[r]));
        }
    }

    // ---- layer 2 (weights bA); prefetch W3 -> bB first ----
    load_bfrag(bB, wimg + W3_OFF, lrow, quad);
    layer64(act, bA, em0, em1, cr0, cr1, lrow, quad);

    // ---- layer 3 (weights bB); prefetch W4 T=0 -> bA + sender ids first ----
    load_bfrag(bA, wimg + W4_OFF, lrow, quad);
    int sn0[4], sn1[4];
#pragma unroll
    for (int r = 0; r < 4; ++r) {
        sn0[r] = s_snd[cr0 + r];
        sn1[r] = s_snd[cr1 + r];
    }
    layer64(act, bB, em0, em1, cr0, cr1, lrow, quad);

    // ---- h gather (32 regs; issued before L4 a-frag reads, hides under T=0)
    float hreg0[4][4], hreg1[4][4];
#pragma unroll
    for (int r = 0; r < 4; ++r) {
        const float* hb0 = h + (size_t)sn0[r] * CH + lrow;
        const float* hb1 = h + (size_t)sn1[r] * CH + lrow;
#pragma unroll
        for (int ntl = 0; ntl < 4; ++ntl) {
            hreg0[r][ntl] = hb0[ntl * 16];
            hreg1[r][ntl] = hb1[ntl * 16];
        }
    }

    // ---- layer 4: 3 thirds (l=0,1,2), T-pipelined weight loads, fused agg ----
    {
        bf16x8 a00 = *(const bf16x8*)(act + em0 * ACT_STRIDE + quad * 8);
        bf16x8 a01 = *(const bf16x8*)(act + em0 * ACT_STRIDE + 32 + quad * 8);
        bf16x8 a10 = *(const bf16x8*)(act + em1 * ACT_STRIDE + quad * 8);
        bf16x8 a11 = *(const bf16x8*)(act + em1 * ACT_STRIDE + 32 + quad * 8);

        load_bfrag(bB, wimg + W4_OFF + 64 * 72, lrow, quad);       // T=1 weights
        l4_third_agg(act, s_rcv, s_sh, agg, bA, a00, a01, a10, a11, hreg0, hreg1,
                     0, cr0, cr1, wr0, lane, lrow, quad);
        load_bfrag(bA, wimg + W4_OFF + 2 * 64 * 72, lrow, quad);   // T=2 weights
        l4_third_agg(act, s_rcv, s_sh, agg, bB, a00, a01, a10, a11, hreg0, hreg1,
                     1, cr0, cr1, wr0, lane, lrow, quad);
        l4_third_agg(act, s_rcv, s_sh, agg, bA, a00, a01, a10, a11, hreg0, hreg1,
                     2, cr0, cr1, wr0, lane, lrow, quad);
    }
}

// ---------- K_down: read agg, apply 1/avg_neigh + linear_down ----------
// One wave per node, lane = channel. agg reads are 9 coalesced 256B segments.
__global__ __launch_bounds__(256, 4) void k_down(const float* __restrict__ agg,
                                                 const float* __restrict__ Wd,
                                                 float* __restrict__ out) {
    __shared__ float sg[4][576];
    int wv = threadIdx.x >> 6;
    int lane = threadIdx.x & 63;
    int node = __builtin_amdgcn_readfirstlane(blockIdx.x * 4 + wv);
    const float* ag = agg + (size_t)node * AGG_STRIDE + lane;
    // stash node's agg tile in LDS (per-wave region; in-order DS => no barrier)
    float* arow = sg[wv];
#pragma unroll
    for (int m = 0; m < 9; ++m) arow[lane * 9 + m] = ag[m * 64] * (1.0f / 32.0f);

    // linear_down: lane = output channel d; arow reads broadcast
    float* orow = out + (size_t)node * 576;
    {
        float a = 0.f;
#pragma unroll
        for (int c = 0; c < 64; ++c) a += arow[c * 9] * Wd[c * 64 + lane];
        orow[lane] = a * 0.125f;
    }
    {
        float m3[3] = {0.f, 0.f, 0.f};
#pragma unroll
        for (int c = 0; c < 64; ++c) {
            float w = Wd[(64 + c) * 64 + lane];
#pragma unroll
            for (int mm = 0; mm < 3; ++mm) m3[mm] += arow[c * 9 + 1 + mm] * w;
        }
#pragma unroll
        for (int mm = 0; mm < 3; ++mm) orow[64 + lane * 3 + mm] = m3[mm] * 0.125f;
    }
    {
        float m5[5] = {0.f, 0.f, 0.f, 0.f, 0.f};
#pragma unroll
        for (int c = 0; c < 64; ++c) {
            float w = Wd[(128 + c) * 64 + lane];
#pragma unroll
            for (int mm = 0; mm < 5; ++mm) m5[mm] += arow[c * 9 + 4 + mm] * w;
        }
#pragma unroll
        for (int mm = 0; mm < 5; ++mm) orow[256 + lane * 5 + mm] = m5[mm] * 0.125f;
    }
}

// ---------- launcher ----------
static inline size_t align256(size_t x) { return (x + 255) & ~(size_t)255; }

extern "C" void kernel_launch(void* const* d_in, const int* in_sizes, int n_in,
                              void* d_out, int out_size, void* d_ws, size_t ws_size,
                              hipStream_t stream) {
    const float* edge_vectors = (const float*)d_in[0];
    const float* node_feats   = (const float*)d_in[1];
    const float* radial       = (const float*)d_in[2];
    const int*   senders      = (const int*)d_in[3];
    const int*   receivers    = (const int*)d_in[4];
    const float* W_up         = (const float*)d_in[5];
    const float* W_mlp1       = (const float*)d_in[6];
    const float* W_mlp2       = (const float*)d_in[7];
    const float* W_mlp3       = (const float*)d_in[8];
    const float* W_mlp4       = (const float*)d_in[9];
    const float* W_down       = (const float*)d_in[10];
    float* out = (float*)d_out;

    char* base = (char*)d_ws;
    size_t off = 0;
    float* h = (float*)(base + off);              off = align256(off + (size_t)N_NODES * CH * 4);
    float* agg = (float*)(base + off);            off = align256(off + (size_t)N_NODES * AGG_STRIDE * 4);
    unsigned short* wimg = (unsigned short*)(base + off); off = align256(off + (size_t)W_TOT * 2);

    hipMemsetAsync(agg, 0, (size_t)N_NODES * AGG_STRIDE * 4, stream);

    k_pre<<<PREP_BLKS + H_BLKS, 256, 0, stream>>>(
        W_mlp1, W_mlp2, W_mlp3, W_mlp4, wimg, node_feats, W_up, h);
    k_mlp<<<N_EDGES / EPB, 256, 0, stream>>>(edge_vectors, radial, wimg, senders,
                                             receivers, h, agg);
    k_down<<<N_NODES / 4, 256, 0, stream>>>(agg, W_down, out);
}